// Round 1
// baseline (885.664 us; speedup 1.0000x reference)
//
#include <hip/hip_runtime.h>
#include <hip/hip_bf16.h>
#include <cstdint>

// ---------------------------------------------------------------------------
// XCA attention: qkv 1x1 conv -> dw3x3 -> l2norm -> 48x48 channel attn -> proj
// Decomposition:
//   K0  transpose+cast  x (f32 [C][P]) -> xT (bf16 [P][C])
//   KW  cast qkv_w -> bf16
//   K1  GEMM qkv = W(1152x384) @ x  (bf16 MFMA, m97-style 128x128/BK64 tile)
//   K2  depthwise 3x3 + bias, writes bf16, accumulates per-row sumsq (q,k)
//   K2b Gram G[b,h] = q @ k^T (unnormalized, MFMA direct-from-global, split-K)
//   K3a logits = temp * G / (|q||k|) -> softmax -> attn
//   K3b W_eff[b] = proj_w @ blockdiag(attn)   (384x384 per batch)
//   K2c transpose v -> vT (bf16 [P][C])       (aliases xT region)
//   K4  out = W_eff @ v + proj_b  (same GEMM kernel, fp32 out)
// ---------------------------------------------------------------------------

#define BATCH 8
#define DIM 384
#define HEADS 8
#define CH 48           // DIM/HEADS
#define HW 16384
#define C3 1152         // 3*DIM

typedef __attribute__((ext_vector_type(8))) short bf16x8;
typedef __attribute__((ext_vector_type(4))) float f32x4;

__device__ __forceinline__ float b2f(ushort b) {
  union { float f; unsigned u; } x; x.u = ((unsigned)b) << 16; return x.f;
}
__device__ __forceinline__ ushort f2b(float f) {
  union { float f; unsigned u; } x; x.f = f;
  unsigned r = x.u + 0x7fffu + ((x.u >> 16) & 1u);
  return (ushort)(r >> 16);
}

// async global->LDS, 16B per lane. LDS dest = wave-uniform base + lane*16.
__device__ __forceinline__ void async16(const ushort* g, ushort* l) {
  __builtin_amdgcn_global_load_lds(
      (const __attribute__((address_space(1))) unsigned int*)(unsigned long long)(uintptr_t)g,
      (__attribute__((address_space(3))) unsigned int*)(unsigned int)(uintptr_t)l,
      16, 0, 0);
}

// ---------------- K0 / K2c: tiled transpose + cast to bf16 ------------------
// src: [C][P] row-major per batch (stride sstride elems), dst: [P][C] bf16
template <typename SrcT>
__global__ __launch_bounds__(256) void transpose_cast(
    const SrcT* __restrict__ src, ushort* __restrict__ dst,
    int C, int P, long sstride, long dstride) {
  __shared__ float t[64][65];
  int b = blockIdx.z;
  src += (size_t)b * sstride;
  dst += (size_t)b * dstride;
  int p0 = blockIdx.x * 64, c0 = blockIdx.y * 64;
  int tid = threadIdx.x;
  int lc = tid >> 2, sg = tid & 3;
#pragma unroll
  for (int j = 0; j < 4; ++j) {
    int col = sg * 4 + j * 16;
    if constexpr (sizeof(SrcT) == 4) {
      const float4 v = *(const float4*)((const float*)src + (size_t)(c0 + lc) * P + p0 + col);
      t[lc][col] = v.x; t[lc][col + 1] = v.y; t[lc][col + 2] = v.z; t[lc][col + 3] = v.w;
    } else {
      const ushort4 v = *(const ushort4*)((const ushort*)src + (size_t)(c0 + lc) * P + p0 + col);
      t[lc][col] = b2f(v.x); t[lc][col + 1] = b2f(v.y); t[lc][col + 2] = b2f(v.z); t[lc][col + 3] = b2f(v.w);
    }
  }
  __syncthreads();
  int lp = tid >> 2;
#pragma unroll
  for (int j = 0; j < 4; ++j) {
    int c = sg * 4 + j * 16;
    ushort4 o = make_ushort4(f2b(t[c][lp]), f2b(t[c + 1][lp]), f2b(t[c + 2][lp]), f2b(t[c + 3][lp]));
    *(ushort4*)(dst + (size_t)(p0 + lp) * C + c0 + c) = o;
  }
}

// ---------------- KW: cast weights to bf16 ----------------------------------
__global__ __launch_bounds__(256) void cast_w(const float* __restrict__ s,
                                              ushort* __restrict__ d, int n) {
  int i = (blockIdx.x * 256 + threadIdx.x) * 4;
  if (i + 3 < n) {
    float4 v = *(const float4*)(s + i);
    ushort4 o = make_ushort4(f2b(v.x), f2b(v.y), f2b(v.z), f2b(v.w));
    *(ushort4*)(d + i) = o;
  }
}

// ---------------- K1/K4: bf16 MFMA GEMM, C[m][n] = A[m][k] * Bt[n][k] -------
// 128x128 tile, BK=64, 4 waves (2x2), 16x16x32 MFMA, global_load_lds staging.
template <int OUT_BF16>
__global__ __launch_bounds__(256) void gemm_nt(
    const ushort* __restrict__ A, const ushort* __restrict__ Bt,
    const float* __restrict__ bias, void* __restrict__ Cout,
    int M, int N, int K, long Asb, long Bsb, long Csb) {
  int zb = blockIdx.z;
  const ushort* Ab = A + (size_t)zb * Asb;
  const ushort* Bb = Bt + (size_t)zb * Bsb;
  int m0 = blockIdx.x * 128, n0 = blockIdx.y * 128;
  __shared__ __align__(16) ushort As[128 * 64];
  __shared__ __align__(16) ushort Bs[128 * 64];
  int tid = threadIdx.x, lane = tid & 63, wid = tid >> 6;
  int srow = lane >> 3, scol = (lane & 7) * 8;
  int wrow = (wid >> 1) * 64, wcol = (wid & 1) * 64;
  int fr = lane & 15, fk = (lane >> 4) * 8;
  f32x4 zero = {0.f, 0.f, 0.f, 0.f};
  f32x4 acc[4][4];
#pragma unroll
  for (int m = 0; m < 4; ++m)
#pragma unroll
    for (int n = 0; n < 4; ++n) acc[m][n] = zero;

  for (int k0 = 0; k0 < K; k0 += 64) {
    __syncthreads();
#pragma unroll
    for (int i = 0; i < 4; ++i) {
      int r = i * 32 + wid * 8 + srow;
      async16(Ab + (size_t)(m0 + r) * K + k0 + scol, &As[(i * 32 + wid * 8) * 64]);
      async16(Bb + (size_t)(n0 + r) * K + k0 + scol, &Bs[(i * 32 + wid * 8) * 64]);
    }
    __syncthreads();
#pragma unroll
    for (int kk = 0; kk < 2; ++kk) {
      bf16x8 af[4], bv[4];
#pragma unroll
      for (int m = 0; m < 4; ++m)
        af[m] = *(const bf16x8*)&As[(wrow + m * 16 + fr) * 64 + kk * 32 + fk];
#pragma unroll
      for (int n = 0; n < 4; ++n)
        bv[n] = *(const bf16x8*)&Bs[(wcol + n * 16 + fr) * 64 + kk * 32 + fk];
#pragma unroll
      for (int m = 0; m < 4; ++m)
#pragma unroll
        for (int n = 0; n < 4; ++n)
          acc[m][n] = __builtin_amdgcn_mfma_f32_16x16x32_bf16(af[m], bv[n], acc[m][n], 0, 0, 0);
    }
  }
  int crow = (lane >> 4) * 4, ccol = lane & 15;
#pragma unroll
  for (int m = 0; m < 4; ++m) {
#pragma unroll
    for (int j = 0; j < 4; ++j) {
      int gr = m0 + wrow + m * 16 + crow + j;
      float bz = bias[gr];
#pragma unroll
      for (int n = 0; n < 4; ++n) {
        int gc = n0 + wcol + n * 16 + ccol;
        float v = acc[m][n][j] + bz;
        if (OUT_BF16)
          ((ushort*)Cout)[(size_t)zb * Csb + (size_t)gr * N + gc] = f2b(v);
        else
          ((float*)Cout)[(size_t)zb * Csb + (size_t)gr * N + gc] = v;
      }
    }
  }
}

// ---------------- K2: depthwise 3x3 + bias + sumsq --------------------------
__global__ __launch_bounds__(256) void dwconv(
    const ushort* __restrict__ in, const float* __restrict__ w9,
    const float* __restrict__ b9, ushort* __restrict__ out,
    float* __restrict__ sq) {
  int rt = blockIdx.x;   // row tile (16 rows)
  int ch = blockIdx.y;   // 0..1151
  int b = blockIdx.z;
  const size_t plane = ((size_t)b * C3 + ch) * HW;
  __shared__ float ld[18 * 132];
  int tid = threadIdx.x;
  int r0 = rt * 16;
  for (int idx = tid; idx < 18 * 130; idx += 256) {
    int lr = idx / 130, lc = idx - lr * 130;
    int gr = r0 - 1 + lr, gc = lc - 1;
    float v = 0.f;
    if ((unsigned)gr < 128u && (unsigned)gc < 128u)
      v = b2f(in[plane + gr * 128 + gc]);
    ld[lr * 132 + lc] = v;
  }
  float wv[9];
#pragma unroll
  for (int i = 0; i < 9; ++i) wv[i] = w9[ch * 9 + i];
  float bias = b9[ch];
  __syncthreads();
  int sr = tid >> 5;
  int cg = (tid & 31) * 4;
  float ss = 0.f;
#pragma unroll
  for (int rr = 0; rr < 2; ++rr) {
    int R = sr * 2 + rr;
    float o[4];
#pragma unroll
    for (int cc = 0; cc < 4; ++cc) {
      float a = bias;
#pragma unroll
      for (int dy = 0; dy < 3; ++dy)
#pragma unroll
        for (int dx = 0; dx < 3; ++dx)
          a += wv[dy * 3 + dx] * ld[(R + dy) * 132 + cg + cc + dx];
      o[cc] = a;
      ss += a * a;
    }
    ushort4 pk = make_ushort4(f2b(o[0]), f2b(o[1]), f2b(o[2]), f2b(o[3]));
    *(ushort4*)(out + plane + (size_t)(r0 + R) * 128 + cg) = pk;
  }
  if (ch < 2 * DIM) {
#pragma unroll
    for (int off = 32; off; off >>= 1) ss += __shfl_down(ss, off, 64);
    if ((tid & 63) == 0) atomicAdd(&sq[b * 2 * DIM + ch], ss);
  }
}

// ---------------- K2b: unnormalized Gram G[b,h] = q @ k^T -------------------
__global__ __launch_bounds__(256) void gram(const ushort* __restrict__ qkvd,
                                            float* __restrict__ G) {
  int chunk = blockIdx.x;  // 0..15 (split-K over pixels)
  int bh = blockIdx.y;     // 0..63
  int b = bh >> 3, h = bh & 7;
  int tid = threadIdx.x, lane = tid & 63, wid = tid >> 6;
  const ushort* qbase = qkvd + ((size_t)b * C3 + h * CH) * HW;
  const ushort* kbase = qbase + (size_t)DIM * HW;
  int pix0 = chunk * 1024 + wid * 256;
  int fr = lane & 15, fk = (lane >> 4) * 8;
  f32x4 zero = {0.f, 0.f, 0.f, 0.f};
  f32x4 acc[3][3];
#pragma unroll
  for (int i = 0; i < 3; ++i)
#pragma unroll
    for (int j = 0; j < 3; ++j) acc[i][j] = zero;
#pragma unroll
  for (int it = 0; it < 8; ++it) {
    int pix = pix0 + it * 32 + fk;
    bf16x8 aq[3], bk[3];
#pragma unroll
    for (int mi = 0; mi < 3; ++mi)
      aq[mi] = *(const bf16x8*)(qbase + (size_t)(mi * 16 + fr) * HW + pix);
#pragma unroll
    for (int ni = 0; ni < 3; ++ni)
      bk[ni] = *(const bf16x8*)(kbase + (size_t)(ni * 16 + fr) * HW + pix);
#pragma unroll
    for (int mi = 0; mi < 3; ++mi)
#pragma unroll
      for (int ni = 0; ni < 3; ++ni)
        acc[mi][ni] = __builtin_amdgcn_mfma_f32_16x16x32_bf16(aq[mi], bk[ni], acc[mi][ni], 0, 0, 0);
  }
  __shared__ float gs[CH * CH];
  for (int i = tid; i < CH * CH; i += 256) gs[i] = 0.f;
  __syncthreads();
  int crow = (lane >> 4) * 4, ccol = lane & 15;
#pragma unroll
  for (int mi = 0; mi < 3; ++mi)
#pragma unroll
    for (int ni = 0; ni < 3; ++ni)
#pragma unroll
      for (int j = 0; j < 4; ++j)
        atomicAdd(&gs[(mi * 16 + crow + j) * CH + ni * 16 + ccol], acc[mi][ni][j]);
  __syncthreads();
  float* Gp = G + (size_t)bh * CH * CH;
  for (int i = tid; i < CH * CH; i += 256) atomicAdd(&Gp[i], gs[i]);
}

// ---------------- K3a: normalize + softmax ----------------------------------
__global__ void softmax_k(const float* __restrict__ G, const float* __restrict__ sq,
                          const float* __restrict__ temp, float* __restrict__ attn) {
  int bh = blockIdx.x, b = bh >> 3, h = bh & 7;
  int lane = threadIdx.x;
  __shared__ float inq[CH], ink[CH];
  if (lane < CH) {
    inq[lane] = 1.f / fmaxf(sqrtf(sq[b * 2 * DIM + h * CH + lane]), 1e-12f);
    ink[lane] = 1.f / fmaxf(sqrtf(sq[b * 2 * DIM + DIM + h * CH + lane]), 1e-12f);
  }
  __syncthreads();
  if (lane < CH) {
    float t = temp[h] * inq[lane];
    const float* g = G + (size_t)bh * CH * CH + lane * CH;
    float v[CH];
    float mx = -1e30f;
#pragma unroll
    for (int d = 0; d < CH; ++d) { v[d] = t * g[d] * ink[d]; mx = fmaxf(mx, v[d]); }
    float s = 0.f;
#pragma unroll
    for (int d = 0; d < CH; ++d) { v[d] = expf(v[d] - mx); s += v[d]; }
    float inv = 1.f / s;
    float* a = attn + (size_t)bh * CH * CH + lane * CH;
#pragma unroll
    for (int d = 0; d < CH; ++d) a[d] = v[d] * inv;
  }
}

// ---------------- K3b: W_eff[b] = proj_w @ blockdiag(attn) ------------------
__global__ __launch_bounds__(384) void weff_k(const float* __restrict__ pw,
                                              const float* __restrict__ attn,
                                              ushort* __restrict__ weff) {
  int dg = threadIdx.x;  // 0..383
  int p = blockIdx.x;    // 0..383
  int b = blockIdx.y;
  int h = dg / CH, d = dg - h * CH;
  const float* a = attn + (((size_t)b * HEADS + h) * CH) * CH + d;
  const float* wrow = pw + (size_t)p * DIM + h * CH;
  float s = 0.f;
#pragma unroll
  for (int c = 0; c < CH; ++c) s += wrow[c] * a[c * CH];
  weff[((size_t)b * DIM + p) * DIM + dg] = f2b(s);
}

// ---------------------------------------------------------------------------
extern "C" void kernel_launch(void* const* d_in, const int* in_sizes, int n_in,
                              void* d_out, int out_size, void* d_ws, size_t ws_size,
                              hipStream_t stream) {
  const float* x = (const float*)d_in[0];
  const float* qkv_w = (const float*)d_in[1];
  const float* qkv_b = (const float*)d_in[2];
  const float* dw_w = (const float*)d_in[3];
  const float* dw_b = (const float*)d_in[4];
  const float* proj_w = (const float*)d_in[5];
  const float* proj_b = (const float*)d_in[6];
  const float* temp = (const float*)d_in[7];

  const size_t SZ_XT = (size_t)BATCH * HW * DIM * 2;      // 100,663,296 (also vT)
  const size_t SZ_C1 = (size_t)BATCH * C3 * HW * 2;       // 301,989,888
  const size_t SZ_WQB = (size_t)C3 * DIM * 2;             // 884,736
  const size_t SZ_SQ = (size_t)BATCH * 2 * DIM * 4;       // 24,576
  const size_t SZ_G = (size_t)BATCH * HEADS * CH * CH * 4;  // 589,824

  const size_t OFF_XT = 0;
  const size_t OFF_C1 = OFF_XT + SZ_XT;
  const size_t OFF_QKVD = OFF_C1 + SZ_C1;
  const size_t OFF_WQB = OFF_QKVD + SZ_C1;
  const size_t OFF_SQ = OFF_WQB + SZ_WQB;
  const size_t OFF_G = OFF_SQ + SZ_SQ;
  const size_t OFF_ATTN = OFF_G + SZ_G;
  const size_t OFF_WEFF = OFF_ATTN + SZ_G;
  const size_t TOTAL = OFF_WEFF + (size_t)BATCH * DIM * DIM * 2;
  if (ws_size < TOTAL) return;  // fail loudly (validation) rather than corrupt

  char* ws = (char*)d_ws;
  ushort* xT = (ushort*)(ws + OFF_XT);   // later reused as vT
  ushort* c1 = (ushort*)(ws + OFF_C1);
  ushort* qkvd = (ushort*)(ws + OFF_QKVD);
  ushort* wqb = (ushort*)(ws + OFF_WQB);
  float* sq = (float*)(ws + OFF_SQ);
  float* G = (float*)(ws + OFF_G);
  float* attn = (float*)(ws + OFF_ATTN);
  ushort* weff = (ushort*)(ws + OFF_WEFF);

  hipMemsetAsync(ws + OFF_SQ, 0, SZ_SQ + SZ_G, stream);

  cast_w<<<(C3 * DIM) / 1024, 256, 0, stream>>>(qkv_w, wqb, C3 * DIM);
  transpose_cast<float><<<dim3(HW / 64, DIM / 64, BATCH), 256, 0, stream>>>(
      x, xT, DIM, HW, (long)DIM * HW, (long)HW * DIM);
  gemm_nt<1><<<dim3(C3 / 128, HW / 128, BATCH), 256, 0, stream>>>(
      wqb, xT, qkv_b, (void*)c1, C3, HW, DIM, 0L, (long)HW * DIM, (long)C3 * HW);
  dwconv<<<dim3(8, C3, BATCH), 256, 0, stream>>>(c1, dw_w, dw_b, qkvd, sq);
  gram<<<dim3(16, BATCH * HEADS), 256, 0, stream>>>(qkvd, G);
  softmax_k<<<BATCH * HEADS, 64, 0, stream>>>(G, sq, temp, attn);
  weff_k<<<dim3(DIM, BATCH), 384, 0, stream>>>(proj_w, attn, weff);
  // transpose v (bf16) into the xT region (xT is dead after K1)
  transpose_cast<ushort><<<dim3(HW / 64, DIM / 64, BATCH), 256, 0, stream>>>(
      qkvd + (size_t)2 * DIM * HW, xT, DIM, HW, (long)C3 * HW, (long)HW * DIM);
  gemm_nt<0><<<dim3(DIM / 128, HW / 128, BATCH), 256, 0, stream>>>(
      weff, xT, proj_b, d_out, DIM, HW, DIM, (long)DIM * DIM, (long)HW * DIM,
      (long)DIM * HW);
}

// Round 3
// 716.132 us; speedup vs baseline: 1.2367x; 1.2367x over previous
//
#include <hip/hip_runtime.h>
#include <hip/hip_bf16.h>
#include <cstdint>

// ---------------------------------------------------------------------------
// XCA attention: qkv 1x1 conv -> dw3x3 -> l2norm -> 48x48 channel attn -> proj
//   K0  transpose+cast  x (f32 [C][P]) -> xT (bf16 [P][C])
//   KW  cast qkv_w -> bf16
//   K1  GEMM qkv = W(1152x384) @ x  (bf16 MFMA, 128x128/BK64 tile)
//   K2  depthwise 3x3 + bias (register-streaming, no LDS), fused sumsq
//   K2b Gram G[b,h] = q @ k^T (unnormalized, MFMA direct-from-global, split-K)
//   K3a logits = temp * G / (|q||k|) -> softmax -> attn
//   K3b W_eff[b] = proj_w @ blockdiag(attn)   (384x384 per batch)
//   K2c transpose v -> vT (bf16 [P][C])       (aliases xT region)
//   K4  out = W_eff @ v + proj_b  (same GEMM kernel, fp32 out)
// ---------------------------------------------------------------------------

#define BATCH 8
#define DIM 384
#define HEADS 8
#define CH 48           // DIM/HEADS
#define HW 16384
#define C3 1152         // 3*DIM

typedef __attribute__((ext_vector_type(8))) short bf16x8;
typedef __attribute__((ext_vector_type(8))) unsigned short u16x8;
typedef __attribute__((ext_vector_type(4))) float f32x4;

__device__ __forceinline__ float b2f(ushort b) {
  union { float f; unsigned u; } x; x.u = ((unsigned)b) << 16; return x.f;
}
__device__ __forceinline__ ushort f2b(float f) {
  union { float f; unsigned u; } x; x.f = f;
  unsigned r = x.u + 0x7fffu + ((x.u >> 16) & 1u);
  return (ushort)(r >> 16);
}

// async global->LDS, 16B per lane. LDS dest = wave-uniform base + lane*16.
__device__ __forceinline__ void async16(const ushort* g, ushort* l) {
  __builtin_amdgcn_global_load_lds(
      (const __attribute__((address_space(1))) unsigned int*)(unsigned long long)(uintptr_t)g,
      (__attribute__((address_space(3))) unsigned int*)(unsigned int)(uintptr_t)l,
      16, 0, 0);
}

// ---------------- K0 / K2c: tiled transpose + cast to bf16 ------------------
// src: [C][P] row-major per batch (stride sstride elems), dst: [P][C] bf16
template <typename SrcT>
__global__ __launch_bounds__(256) void transpose_cast(
    const SrcT* __restrict__ src, ushort* __restrict__ dst,
    int C, int P, long sstride, long dstride) {
  __shared__ float t[64][65];
  int b = blockIdx.z;
  src += (size_t)b * sstride;
  dst += (size_t)b * dstride;
  int p0 = blockIdx.x * 64, c0 = blockIdx.y * 64;
  int tid = threadIdx.x;
  int lc = tid >> 2, sg = tid & 3;
#pragma unroll
  for (int j = 0; j < 4; ++j) {
    int col = sg * 4 + j * 16;
    if constexpr (sizeof(SrcT) == 4) {
      const float4 v = *(const float4*)((const float*)src + (size_t)(c0 + lc) * P + p0 + col);
      t[lc][col] = v.x; t[lc][col + 1] = v.y; t[lc][col + 2] = v.z; t[lc][col + 3] = v.w;
    } else {
      const ushort4 v = *(const ushort4*)((const ushort*)src + (size_t)(c0 + lc) * P + p0 + col);
      t[lc][col] = b2f(v.x); t[lc][col + 1] = b2f(v.y); t[lc][col + 2] = b2f(v.z); t[lc][col + 3] = b2f(v.w);
    }
  }
  __syncthreads();
  int lp = tid >> 2;
#pragma unroll
  for (int j = 0; j < 4; ++j) {
    int c = sg * 4 + j * 16;
    ushort4 o = make_ushort4(f2b(t[c][lp]), f2b(t[c + 1][lp]), f2b(t[c + 2][lp]), f2b(t[c + 3][lp]));
    *(ushort4*)(dst + (size_t)(p0 + lp) * C + c0 + c) = o;
  }
}

// ---------------- KW: cast weights to bf16 ----------------------------------
__global__ __launch_bounds__(256) void cast_w(const float* __restrict__ s,
                                              ushort* __restrict__ d, int n) {
  int i = (blockIdx.x * 256 + threadIdx.x) * 4;
  if (i + 3 < n) {
    float4 v = *(const float4*)(s + i);
    ushort4 o = make_ushort4(f2b(v.x), f2b(v.y), f2b(v.z), f2b(v.w));
    *(ushort4*)(d + i) = o;
  }
}

// ---------------- K1/K4: bf16 MFMA GEMM, C[m][n] = A[m][k] * Bt[n][k] -------
// 128x128 tile, BK=64, 4 waves (2x2), 16x16x32 MFMA, global_load_lds staging.
template <int OUT_BF16>
__global__ __launch_bounds__(256) void gemm_nt(
    const ushort* __restrict__ A, const ushort* __restrict__ Bt,
    const float* __restrict__ bias, void* __restrict__ Cout,
    int M, int N, int K, long Asb, long Bsb, long Csb) {
  int zb = blockIdx.z;
  const ushort* Ab = A + (size_t)zb * Asb;
  const ushort* Bb = Bt + (size_t)zb * Bsb;
  int m0 = blockIdx.x * 128, n0 = blockIdx.y * 128;
  __shared__ __align__(16) ushort As[128 * 64];
  __shared__ __align__(16) ushort Bs[128 * 64];
  int tid = threadIdx.x, lane = tid & 63, wid = tid >> 6;
  int srow = lane >> 3, scol = (lane & 7) * 8;
  int wrow = (wid >> 1) * 64, wcol = (wid & 1) * 64;
  int fr = lane & 15, fk = (lane >> 4) * 8;
  f32x4 zero = {0.f, 0.f, 0.f, 0.f};
  f32x4 acc[4][4];
#pragma unroll
  for (int m = 0; m < 4; ++m)
#pragma unroll
    for (int n = 0; n < 4; ++n) acc[m][n] = zero;

  for (int k0 = 0; k0 < K; k0 += 64) {
    __syncthreads();
#pragma unroll
    for (int i = 0; i < 4; ++i) {
      int r = i * 32 + wid * 8 + srow;
      async16(Ab + (size_t)(m0 + r) * K + k0 + scol, &As[(i * 32 + wid * 8) * 64]);
      async16(Bb + (size_t)(n0 + r) * K + k0 + scol, &Bs[(i * 32 + wid * 8) * 64]);
    }
    __syncthreads();
#pragma unroll
    for (int kk = 0; kk < 2; ++kk) {
      bf16x8 af[4], bv[4];
#pragma unroll
      for (int m = 0; m < 4; ++m)
        af[m] = *(const bf16x8*)&As[(wrow + m * 16 + fr) * 64 + kk * 32 + fk];
#pragma unroll
      for (int n = 0; n < 4; ++n)
        bv[n] = *(const bf16x8*)&Bs[(wcol + n * 16 + fr) * 64 + kk * 32 + fk];
#pragma unroll
      for (int m = 0; m < 4; ++m)
#pragma unroll
        for (int n = 0; n < 4; ++n)
          acc[m][n] = __builtin_amdgcn_mfma_f32_16x16x32_bf16(af[m], bv[n], acc[m][n], 0, 0, 0);
    }
  }
  int crow = (lane >> 4) * 4, ccol = lane & 15;
#pragma unroll
  for (int m = 0; m < 4; ++m) {
#pragma unroll
    for (int j = 0; j < 4; ++j) {
      int gr = m0 + wrow + m * 16 + crow + j;
      float bz = bias[gr];
#pragma unroll
      for (int n = 0; n < 4; ++n) {
        int gc = n0 + wcol + n * 16 + ccol;
        float v = acc[m][n][j] + bz;
        if (OUT_BF16)
          ((ushort*)Cout)[(size_t)zb * Csb + (size_t)gr * N + gc] = f2b(v);
        else
          ((float*)Cout)[(size_t)zb * Csb + (size_t)gr * N + gc] = v;
      }
    }
  }
}

// ---------------- K2: depthwise 3x3 + bias + sumsq (register streaming) -----
// One block per (ch, b) plane. Thread layout: rg = tid>>4 (8-row strip),
// cg = tid&15 (8-col group). Stream 10 input rows through registers; halo via
// __shfl from adjacent lanes; rolling 3-row accumulator recurrence.
// Emit only when it >= 2: R = r0 + it - 2 in [r0, r0+7] (owned rows exactly).
__global__ __launch_bounds__(256) void dwconv(
    const ushort* __restrict__ in, const float* __restrict__ w9,
    const float* __restrict__ b9, ushort* __restrict__ out,
    float* __restrict__ sq) {
  int ch = blockIdx.x;   // 0..1151
  int b = blockIdx.y;
  const size_t plane = ((size_t)b * C3 + ch) * HW;
  int tid = threadIdx.x, lane = tid & 63;
  int rg = tid >> 4, cg = tid & 15;
  int r0 = rg * 8, c0 = cg * 8;

  float w[9];
#pragma unroll
  for (int i = 0; i < 9; ++i) w[i] = w9[ch * 9 + i];
  float bias = b9[ch];

  float a0[8], a1[8];
#pragma unroll
  for (int c = 0; c < 8; ++c) { a0[c] = 0.f; a1[c] = 0.f; }
  float ss = 0.f;

#pragma unroll
  for (int it = 0; it < 10; ++it) {
    int r = r0 - 1 + it;
    float x[8];
    if ((unsigned)r < 128u) {
      u16x8 raw = *(const u16x8*)(in + plane + (size_t)r * 128 + c0);
#pragma unroll
      for (int c = 0; c < 8; ++c) x[c] = b2f(raw[c]);
    } else {
#pragma unroll
      for (int c = 0; c < 8; ++c) x[c] = 0.f;
    }
    float xl = __shfl(x[7], lane - 1);
    float xr = __shfl(x[0], lane + 1);
    if (cg == 0) xl = 0.f;
    if (cg == 15) xr = 0.f;

    float h0[8], h1[8], h2[8];
#pragma unroll
    for (int c = 0; c < 8; ++c) {
      float l = (c == 0) ? xl : x[c - 1];
      float rt = (c == 7) ? xr : x[c + 1];
      h0[c] = w[0] * l + w[1] * x[c] + w[2] * rt;
      h1[c] = w[3] * l + w[4] * x[c] + w[5] * rt;
      h2[c] = w[6] * l + w[7] * x[c] + w[8] * rt;
    }
    if (it >= 2) {
      int R = r - 1;  // output row, in [r0, r0+7]
      u16x8 pk;
#pragma unroll
      for (int c = 0; c < 8; ++c) {
        float o = a0[c] + h2[c] + bias;
        ss += o * o;
        pk[c] = f2b(o);
      }
      *(u16x8*)(out + plane + (size_t)R * 128 + c0) = pk;
    }
#pragma unroll
    for (int c = 0; c < 8; ++c) { a0[c] = a1[c] + h1[c]; a1[c] = h0[c]; }
  }

  if (ch < 2 * DIM) {
#pragma unroll
    for (int off = 32; off; off >>= 1) ss += __shfl_down(ss, off, 64);
    if (lane == 0) atomicAdd(&sq[b * 2 * DIM + ch], ss);
  }
}

// ---------------- K2b: unnormalized Gram G[b,h] = q @ k^T -------------------
__global__ __launch_bounds__(256) void gram(const ushort* __restrict__ qkvd,
                                            float* __restrict__ G) {
  int chunk = blockIdx.x;  // 0..15 (split-K over pixels)
  int bh = blockIdx.y;     // 0..63
  int b = bh >> 3, h = bh & 7;
  int tid = threadIdx.x, lane = tid & 63, wid = tid >> 6;
  const ushort* qbase = qkvd + ((size_t)b * C3 + h * CH) * HW;
  const ushort* kbase = qbase + (size_t)DIM * HW;
  int pix0 = chunk * 1024 + wid * 256;
  int fr = lane & 15, fk = (lane >> 4) * 8;
  f32x4 zero = {0.f, 0.f, 0.f, 0.f};
  f32x4 acc[3][3];
#pragma unroll
  for (int i = 0; i < 3; ++i)
#pragma unroll
    for (int j = 0; j < 3; ++j) acc[i][j] = zero;
#pragma unroll
  for (int it = 0; it < 8; ++it) {
    int pix = pix0 + it * 32 + fk;
    bf16x8 aq[3], bk[3];
#pragma unroll
    for (int mi = 0; mi < 3; ++mi)
      aq[mi] = *(const bf16x8*)(qbase + (size_t)(mi * 16 + fr) * HW + pix);
#pragma unroll
    for (int ni = 0; ni < 3; ++ni)
      bk[ni] = *(const bf16x8*)(kbase + (size_t)(ni * 16 + fr) * HW + pix);
#pragma unroll
    for (int mi = 0; mi < 3; ++mi)
#pragma unroll
      for (int ni = 0; ni < 3; ++ni)
        acc[mi][ni] = __builtin_amdgcn_mfma_f32_16x16x32_bf16(aq[mi], bk[ni], acc[mi][ni], 0, 0, 0);
  }
  __shared__ float gs[CH * CH];
  for (int i = tid; i < CH * CH; i += 256) gs[i] = 0.f;
  __syncthreads();
  int crow = (lane >> 4) * 4, ccol = lane & 15;
#pragma unroll
  for (int mi = 0; mi < 3; ++mi)
#pragma unroll
    for (int ni = 0; ni < 3; ++ni)
#pragma unroll
      for (int j = 0; j < 4; ++j)
        atomicAdd(&gs[(mi * 16 + crow + j) * CH + ni * 16 + ccol], acc[mi][ni][j]);
  __syncthreads();
  float* Gp = G + (size_t)bh * CH * CH;
  for (int i = tid; i < CH * CH; i += 256) atomicAdd(&Gp[i], gs[i]);
}

// ---------------- K3a: normalize + softmax ----------------------------------
__global__ void softmax_k(const float* __restrict__ G, const float* __restrict__ sq,
                          const float* __restrict__ temp, float* __restrict__ attn) {
  int bh = blockIdx.x, b = bh >> 3, h = bh & 7;
  int lane = threadIdx.x;
  __shared__ float inq[CH], ink[CH];
  if (lane < CH) {
    inq[lane] = 1.f / fmaxf(sqrtf(sq[b * 2 * DIM + h * CH + lane]), 1e-12f);
    ink[lane] = 1.f / fmaxf(sqrtf(sq[b * 2 * DIM + DIM + h * CH + lane]), 1e-12f);
  }
  __syncthreads();
  if (lane < CH) {
    float t = temp[h] * inq[lane];
    const float* g = G + (size_t)bh * CH * CH + lane * CH;
    float v[CH];
    float mx = -1e30f;
#pragma unroll
    for (int d = 0; d < CH; ++d) { v[d] = t * g[d] * ink[d]; mx = fmaxf(mx, v[d]); }
    float s = 0.f;
#pragma unroll
    for (int d = 0; d < CH; ++d) { v[d] = expf(v[d] - mx); s += v[d]; }
    float inv = 1.f / s;
    float* a = attn + (size_t)bh * CH * CH + lane * CH;
#pragma unroll
    for (int d = 0; d < CH; ++d) a[d] = v[d] * inv;
  }
}

// ---------------- K3b: W_eff[b] = proj_w @ blockdiag(attn) ------------------
__global__ __launch_bounds__(384) void weff_k(const float* __restrict__ pw,
                                              const float* __restrict__ attn,
                                              ushort* __restrict__ weff) {
  int dg = threadIdx.x;  // 0..383
  int p = blockIdx.x;    // 0..383
  int b = blockIdx.y;
  int h = dg / CH, d = dg - h * CH;
  const float* a = attn + (((size_t)b * HEADS + h) * CH) * CH + d;
  const float* wrow = pw + (size_t)p * DIM + h * CH;
  float s = 0.f;
#pragma unroll
  for (int c = 0; c < CH; ++c) s += wrow[c] * a[c * CH];
  weff[((size_t)b * DIM + p) * DIM + dg] = f2b(s);
}

// ---------------------------------------------------------------------------
extern "C" void kernel_launch(void* const* d_in, const int* in_sizes, int n_in,
                              void* d_out, int out_size, void* d_ws, size_t ws_size,
                              hipStream_t stream) {
  const float* x = (const float*)d_in[0];
  const float* qkv_w = (const float*)d_in[1];
  const float* qkv_b = (const float*)d_in[2];
  const float* dw_w = (const float*)d_in[3];
  const float* dw_b = (const float*)d_in[4];
  const float* proj_w = (const float*)d_in[5];
  const float* proj_b = (const float*)d_in[6];
  const float* temp = (const float*)d_in[7];

  const size_t SZ_XT = (size_t)BATCH * HW * DIM * 2;      // 100,663,296 (also vT)
  const size_t SZ_C1 = (size_t)BATCH * C3 * HW * 2;       // 301,989,888
  const size_t SZ_WQB = (size_t)C3 * DIM * 2;             // 884,736
  const size_t SZ_SQ = (size_t)BATCH * 2 * DIM * 4;       // 24,576
  const size_t SZ_G = (size_t)BATCH * HEADS * CH * CH * 4;  // 589,824

  const size_t OFF_XT = 0;
  const size_t OFF_C1 = OFF_XT + SZ_XT;
  const size_t OFF_QKVD = OFF_C1 + SZ_C1;
  const size_t OFF_WQB = OFF_QKVD + SZ_C1;
  const size_t OFF_SQ = OFF_WQB + SZ_WQB;
  const size_t OFF_G = OFF_SQ + SZ_SQ;
  const size_t OFF_ATTN = OFF_G + SZ_G;
  const size_t OFF_WEFF = OFF_ATTN + SZ_G;
  const size_t TOTAL = OFF_WEFF + (size_t)BATCH * DIM * DIM * 2;
  if (ws_size < TOTAL) return;  // fail loudly (validation) rather than corrupt

  char* ws = (char*)d_ws;
  ushort* xT = (ushort*)(ws + OFF_XT);   // later reused as vT
  ushort* c1 = (ushort*)(ws + OFF_C1);
  ushort* qkvd = (ushort*)(ws + OFF_QKVD);
  ushort* wqb = (ushort*)(ws + OFF_WQB);
  float* sq = (float*)(ws + OFF_SQ);
  float* G = (float*)(ws + OFF_G);
  float* attn = (float*)(ws + OFF_ATTN);
  ushort* weff = (ushort*)(ws + OFF_WEFF);

  hipMemsetAsync(ws + OFF_SQ, 0, SZ_SQ + SZ_G, stream);

  cast_w<<<(C3 * DIM) / 1024, 256, 0, stream>>>(qkv_w, wqb, C3 * DIM);
  transpose_cast<float><<<dim3(HW / 64, DIM / 64, BATCH), 256, 0, stream>>>(
      x, xT, DIM, HW, (long)DIM * HW, (long)HW * DIM);
  gemm_nt<1><<<dim3(C3 / 128, HW / 128, BATCH), 256, 0, stream>>>(
      wqb, xT, qkv_b, (void*)c1, C3, HW, DIM, 0L, (long)HW * DIM, (long)C3 * HW);
  dwconv<<<dim3(C3, BATCH), 256, 0, stream>>>(c1, dw_w, dw_b, qkvd, sq);
  gram<<<dim3(16, BATCH * HEADS), 256, 0, stream>>>(qkvd, G);
  softmax_k<<<BATCH * HEADS, 64, 0, stream>>>(G, sq, temp, attn);
  weff_k<<<dim3(DIM, BATCH), 384, 0, stream>>>(proj_w, attn, weff);
  // transpose v (bf16) into the xT region (xT is dead after K1)
  transpose_cast<ushort><<<dim3(HW / 64, DIM / 64, BATCH), 256, 0, stream>>>(
      qkvd + (size_t)2 * DIM * HW, xT, DIM, HW, (long)C3 * HW, (long)HW * DIM);
  gemm_nt<0><<<dim3(DIM / 128, HW / 128, BATCH), 256, 0, stream>>>(
      weff, xT, proj_b, d_out, DIM, HW, DIM, (long)DIM * DIM, (long)HW * DIM,
      (long)DIM * HW);
}

// Round 4
// 672.341 us; speedup vs baseline: 1.3173x; 1.0651x over previous
//
#include <hip/hip_runtime.h>
#include <hip/hip_bf16.h>
#include <cstdint>

// ---------------------------------------------------------------------------
// XCA attention: qkv 1x1 conv -> dw3x3 -> l2norm -> 48x48 channel attn -> proj
//   K0  transpose+cast  x (f32 [C][P]) -> xT (bf16 [P][C])
//   KW  cast qkv_w -> bf16
//   K1  GEMM qkv = W(1152x384) @ x  (bf16 MFMA, 128x128/BK64, 2-phase dbuf)
//   K2  depthwise 3x3 + bias (register-streaming, no LDS), fused sumsq
//   K2b Gram G[b,h] = q @ k^T (unnormalized, MFMA direct-from-global, split-K)
//   K3a logits = temp * G / (|q||k|) -> softmax -> attn
//   K3b W_eff[b] = proj_w @ blockdiag(attn)   (384x384 per batch)
//   K2c transpose v -> vT (bf16 [P][C])       (aliases xT region)
//   K4  out = W_eff @ v + proj_b  (same GEMM kernel, fp32 out)
// ---------------------------------------------------------------------------

#define BATCH 8
#define DIM 384
#define HEADS 8
#define CH 48           // DIM/HEADS
#define HW 16384
#define C3 1152         // 3*DIM

typedef __attribute__((ext_vector_type(8))) short bf16x8;
typedef __attribute__((ext_vector_type(8))) unsigned short u16x8;
typedef __attribute__((ext_vector_type(4))) float f32x4;

__device__ __forceinline__ float b2f(ushort b) {
  union { float f; unsigned u; } x; x.u = ((unsigned)b) << 16; return x.f;
}
__device__ __forceinline__ ushort f2b(float f) {
  union { float f; unsigned u; } x; x.f = f;
  unsigned r = x.u + 0x7fffu + ((x.u >> 16) & 1u);
  return (ushort)(r >> 16);
}

// async global->LDS, 16B per lane. LDS dest = wave-uniform base + lane*16.
__device__ __forceinline__ void async16(const ushort* g, ushort* l) {
  __builtin_amdgcn_global_load_lds(
      (const __attribute__((address_space(1))) unsigned int*)(unsigned long long)(uintptr_t)g,
      (__attribute__((address_space(3))) unsigned int*)(unsigned int)(uintptr_t)l,
      16, 0, 0);
}

// ---------------- K0 / K2c: tiled transpose + cast to bf16 ------------------
// src: [C][P] row-major per batch (stride sstride elems), dst: [P][C] bf16
template <typename SrcT>
__global__ __launch_bounds__(256) void transpose_cast(
    const SrcT* __restrict__ src, ushort* __restrict__ dst,
    int C, int P, long sstride, long dstride) {
  __shared__ float t[64][65];
  int b = blockIdx.z;
  src += (size_t)b * sstride;
  dst += (size_t)b * dstride;
  int p0 = blockIdx.x * 64, c0 = blockIdx.y * 64;
  int tid = threadIdx.x;
  int lc = tid >> 2, sg = tid & 3;
#pragma unroll
  for (int j = 0; j < 4; ++j) {
    int col = sg * 4 + j * 16;
    if constexpr (sizeof(SrcT) == 4) {
      const float4 v = *(const float4*)((const float*)src + (size_t)(c0 + lc) * P + p0 + col);
      t[lc][col] = v.x; t[lc][col + 1] = v.y; t[lc][col + 2] = v.z; t[lc][col + 3] = v.w;
    } else {
      const ushort4 v = *(const ushort4*)((const ushort*)src + (size_t)(c0 + lc) * P + p0 + col);
      t[lc][col] = b2f(v.x); t[lc][col + 1] = b2f(v.y); t[lc][col + 2] = b2f(v.z); t[lc][col + 3] = b2f(v.w);
    }
  }
  __syncthreads();
  int lp = tid >> 2;
#pragma unroll
  for (int j = 0; j < 4; ++j) {
    int c = sg * 4 + j * 16;
    ushort4 o = make_ushort4(f2b(t[c][lp]), f2b(t[c + 1][lp]), f2b(t[c + 2][lp]), f2b(t[c + 3][lp]));
    *(ushort4*)(dst + (size_t)(p0 + lp) * C + c0 + c) = o;
  }
}

// ---------------- KW: cast weights to bf16 ----------------------------------
__global__ __launch_bounds__(256) void cast_w(const float* __restrict__ s,
                                              ushort* __restrict__ d, int n) {
  int i = (blockIdx.x * 256 + threadIdx.x) * 4;
  if (i + 3 < n) {
    float4 v = *(const float4*)(s + i);
    ushort4 o = make_ushort4(f2b(v.x), f2b(v.y), f2b(v.z), f2b(v.w));
    *(ushort4*)(d + i) = o;
  }
}

// ---------------- K1/K4: bf16 MFMA GEMM, C[m][n] = A[m][k] * Bt[n][k] -------
// 128x128 tile, BK=64, 4 waves (2x2), 16x16x32 MFMA.
// 2-phase double-buffered pipeline (T3 minimum): stage(t+1) issued BEFORE
// compute(t); ONE __syncthreads per K-step (its vmcnt(0) drain lands after a
// full compute-phase of overlap instead of immediately after issue).
template <int OUT_BF16>
__global__ __launch_bounds__(256) void gemm_nt(
    const ushort* __restrict__ A, const ushort* __restrict__ Bt,
    const float* __restrict__ bias, void* __restrict__ Cout,
    int M, int N, int K, long Asb, long Bsb, long Csb) {
  int zb = blockIdx.z;
  const ushort* Ab = A + (size_t)zb * Asb;
  const ushort* Bb = Bt + (size_t)zb * Bsb;
  int m0 = blockIdx.x * 128, n0 = blockIdx.y * 128;
  __shared__ __align__(16) ushort As[2][128 * 64];
  __shared__ __align__(16) ushort Bs[2][128 * 64];
  int tid = threadIdx.x, lane = tid & 63, wid = tid >> 6;
  int srow = lane >> 3, scol = (lane & 7) * 8;
  int wrow = (wid >> 1) * 64, wcol = (wid & 1) * 64;
  int fr = lane & 15, fk = (lane >> 4) * 8;
  f32x4 zero = {0.f, 0.f, 0.f, 0.f};
  f32x4 acc[4][4];
#pragma unroll
  for (int m = 0; m < 4; ++m)
#pragma unroll
    for (int n = 0; n < 4; ++n) acc[m][n] = zero;

  auto stage = [&](int buf, int k0) {
#pragma unroll
    for (int i = 0; i < 4; ++i) {
      int r = i * 32 + wid * 8 + srow;
      async16(Ab + (size_t)(m0 + r) * K + k0 + scol, &As[buf][(i * 32 + wid * 8) * 64]);
      async16(Bb + (size_t)(n0 + r) * K + k0 + scol, &Bs[buf][(i * 32 + wid * 8) * 64]);
    }
  };
  auto compute = [&](int buf) {
#pragma unroll
    for (int kk = 0; kk < 2; ++kk) {
      bf16x8 af[4], bv[4];
#pragma unroll
      for (int m = 0; m < 4; ++m)
        af[m] = *(const bf16x8*)&As[buf][(wrow + m * 16 + fr) * 64 + kk * 32 + fk];
#pragma unroll
      for (int n = 0; n < 4; ++n)
        bv[n] = *(const bf16x8*)&Bs[buf][(wcol + n * 16 + fr) * 64 + kk * 32 + fk];
#pragma unroll
      for (int m = 0; m < 4; ++m)
#pragma unroll
        for (int n = 0; n < 4; ++n)
          acc[m][n] = __builtin_amdgcn_mfma_f32_16x16x32_bf16(af[m], bv[n], acc[m][n], 0, 0, 0);
    }
  };

  int NT = K >> 6;
  stage(0, 0);
  __syncthreads();                 // drain prologue stage
  int cur = 0;
  for (int t = 0; t < NT - 1; ++t) {
    stage(cur ^ 1, (t + 1) << 6);  // issue next tile's loads (stay in flight)
    __builtin_amdgcn_s_setprio(1);
    compute(cur);
    __builtin_amdgcn_s_setprio(0);
    __syncthreads();               // vmcnt(0)+barrier: prefetch landed, all read
    cur ^= 1;
  }
  __builtin_amdgcn_s_setprio(1);
  compute(cur);
  __builtin_amdgcn_s_setprio(0);

  int crow = (lane >> 4) * 4, ccol = lane & 15;
#pragma unroll
  for (int m = 0; m < 4; ++m) {
#pragma unroll
    for (int j = 0; j < 4; ++j) {
      int gr = m0 + wrow + m * 16 + crow + j;
      float bz = bias[gr];
#pragma unroll
      for (int n = 0; n < 4; ++n) {
        int gc = n0 + wcol + n * 16 + ccol;
        float v = acc[m][n][j] + bz;
        if (OUT_BF16)
          ((ushort*)Cout)[(size_t)zb * Csb + (size_t)gr * N + gc] = f2b(v);
        else
          ((float*)Cout)[(size_t)zb * Csb + (size_t)gr * N + gc] = v;
      }
    }
  }
}

// ---------------- K2: depthwise 3x3 + bias + sumsq (register streaming) -----
// One block per (ch, b) plane. Thread layout: rg = tid>>4 (8-row strip),
// cg = tid&15 (8-col group). Stream 10 input rows through registers; halo via
// __shfl from adjacent lanes; rolling 3-row accumulator recurrence.
// Emit only when it >= 2: R = r0 + it - 2 in [r0, r0+7] (owned rows exactly).
__global__ __launch_bounds__(256) void dwconv(
    const ushort* __restrict__ in, const float* __restrict__ w9,
    const float* __restrict__ b9, ushort* __restrict__ out,
    float* __restrict__ sq) {
  int ch = blockIdx.x;   // 0..1151
  int b = blockIdx.y;
  const size_t plane = ((size_t)b * C3 + ch) * HW;
  int tid = threadIdx.x, lane = tid & 63;
  int rg = tid >> 4, cg = tid & 15;
  int r0 = rg * 8, c0 = cg * 8;

  float w[9];
#pragma unroll
  for (int i = 0; i < 9; ++i) w[i] = w9[ch * 9 + i];
  float bias = b9[ch];

  float a0[8], a1[8];
#pragma unroll
  for (int c = 0; c < 8; ++c) { a0[c] = 0.f; a1[c] = 0.f; }
  float ss = 0.f;

#pragma unroll
  for (int it = 0; it < 10; ++it) {
    int r = r0 - 1 + it;
    float x[8];
    if ((unsigned)r < 128u) {
      u16x8 raw = *(const u16x8*)(in + plane + (size_t)r * 128 + c0);
#pragma unroll
      for (int c = 0; c < 8; ++c) x[c] = b2f(raw[c]);
    } else {
#pragma unroll
      for (int c = 0; c < 8; ++c) x[c] = 0.f;
    }
    float xl = __shfl(x[7], lane - 1);
    float xr = __shfl(x[0], lane + 1);
    if (cg == 0) xl = 0.f;
    if (cg == 15) xr = 0.f;

    float h0[8], h1[8], h2[8];
#pragma unroll
    for (int c = 0; c < 8; ++c) {
      float l = (c == 0) ? xl : x[c - 1];
      float rt = (c == 7) ? xr : x[c + 1];
      h0[c] = w[0] * l + w[1] * x[c] + w[2] * rt;
      h1[c] = w[3] * l + w[4] * x[c] + w[5] * rt;
      h2[c] = w[6] * l + w[7] * x[c] + w[8] * rt;
    }
    if (it >= 2) {
      int R = r - 1;  // output row, in [r0, r0+7]
      u16x8 pk;
#pragma unroll
      for (int c = 0; c < 8; ++c) {
        float o = a0[c] + h2[c] + bias;
        ss += o * o;
        pk[c] = f2b(o);
      }
      *(u16x8*)(out + plane + (size_t)R * 128 + c0) = pk;
    }
#pragma unroll
    for (int c = 0; c < 8; ++c) { a0[c] = a1[c] + h1[c]; a1[c] = h0[c]; }
  }

  if (ch < 2 * DIM) {
#pragma unroll
    for (int off = 32; off; off >>= 1) ss += __shfl_down(ss, off, 64);
    if (lane == 0) atomicAdd(&sq[b * 2 * DIM + ch], ss);
  }
}

// ---------------- K2b: unnormalized Gram G[b,h] = q @ k^T -------------------
__global__ __launch_bounds__(256) void gram(const ushort* __restrict__ qkvd,
                                            float* __restrict__ G) {
  int chunk = blockIdx.x;  // 0..15 (split-K over pixels)
  int bh = blockIdx.y;     // 0..63
  int b = bh >> 3, h = bh & 7;
  int tid = threadIdx.x, lane = tid & 63, wid = tid >> 6;
  const ushort* qbase = qkvd + ((size_t)b * C3 + h * CH) * HW;
  const ushort* kbase = qbase + (size_t)DIM * HW;
  int pix0 = chunk * 1024 + wid * 256;
  int fr = lane & 15, fk = (lane >> 4) * 8;
  f32x4 zero = {0.f, 0.f, 0.f, 0.f};
  f32x4 acc[3][3];
#pragma unroll
  for (int i = 0; i < 3; ++i)
#pragma unroll
    for (int j = 0; j < 3; ++j) acc[i][j] = zero;
#pragma unroll
  for (int it = 0; it < 8; ++it) {
    int pix = pix0 + it * 32 + fk;
    bf16x8 aq[3], bk[3];
#pragma unroll
    for (int mi = 0; mi < 3; ++mi)
      aq[mi] = *(const bf16x8*)(qbase + (size_t)(mi * 16 + fr) * HW + pix);
#pragma unroll
    for (int ni = 0; ni < 3; ++ni)
      bk[ni] = *(const bf16x8*)(kbase + (size_t)(ni * 16 + fr) * HW + pix);
#pragma unroll
    for (int mi = 0; mi < 3; ++mi)
#pragma unroll
      for (int ni = 0; ni < 3; ++ni)
        acc[mi][ni] = __builtin_amdgcn_mfma_f32_16x16x32_bf16(aq[mi], bk[ni], acc[mi][ni], 0, 0, 0);
  }
  __shared__ float gs[CH * CH];
  for (int i = tid; i < CH * CH; i += 256) gs[i] = 0.f;
  __syncthreads();
  int crow = (lane >> 4) * 4, ccol = lane & 15;
#pragma unroll
  for (int mi = 0; mi < 3; ++mi)
#pragma unroll
    for (int ni = 0; ni < 3; ++ni)
#pragma unroll
      for (int j = 0; j < 4; ++j)
        atomicAdd(&gs[(mi * 16 + crow + j) * CH + ni * 16 + ccol], acc[mi][ni][j]);
  __syncthreads();
  float* Gp = G + (size_t)bh * CH * CH;
  for (int i = tid; i < CH * CH; i += 256) atomicAdd(&Gp[i], gs[i]);
}

// ---------------- K3a: normalize + softmax ----------------------------------
__global__ void softmax_k(const float* __restrict__ G, const float* __restrict__ sq,
                          const float* __restrict__ temp, float* __restrict__ attn) {
  int bh = blockIdx.x, b = bh >> 3, h = bh & 7;
  int lane = threadIdx.x;
  __shared__ float inq[CH], ink[CH];
  if (lane < CH) {
    inq[lane] = 1.f / fmaxf(sqrtf(sq[b * 2 * DIM + h * CH + lane]), 1e-12f);
    ink[lane] = 1.f / fmaxf(sqrtf(sq[b * 2 * DIM + DIM + h * CH + lane]), 1e-12f);
  }
  __syncthreads();
  if (lane < CH) {
    float t = temp[h] * inq[lane];
    const float* g = G + (size_t)bh * CH * CH + lane * CH;
    float v[CH];
    float mx = -1e30f;
#pragma unroll
    for (int d = 0; d < CH; ++d) { v[d] = t * g[d] * ink[d]; mx = fmaxf(mx, v[d]); }
    float s = 0.f;
#pragma unroll
    for (int d = 0; d < CH; ++d) { v[d] = expf(v[d] - mx); s += v[d]; }
    float inv = 1.f / s;
    float* a = attn + (size_t)bh * CH * CH + lane * CH;
#pragma unroll
    for (int d = 0; d < CH; ++d) a[d] = v[d] * inv;
  }
}

// ---------------- K3b: W_eff[b] = proj_w @ blockdiag(attn) ------------------
__global__ __launch_bounds__(384) void weff_k(const float* __restrict__ pw,
                                              const float* __restrict__ attn,
                                              ushort* __restrict__ weff) {
  int dg = threadIdx.x;  // 0..383
  int p = blockIdx.x;    // 0..383
  int b = blockIdx.y;
  int h = dg / CH, d = dg - h * CH;
  const float* a = attn + (((size_t)b * HEADS + h) * CH) * CH + d;
  const float* wrow = pw + (size_t)p * DIM + h * CH;
  float s = 0.f;
#pragma unroll
  for (int c = 0; c < CH; ++c) s += wrow[c] * a[c * CH];
  weff[((size_t)b * DIM + p) * DIM + dg] = f2b(s);
}

// ---------------------------------------------------------------------------
extern "C" void kernel_launch(void* const* d_in, const int* in_sizes, int n_in,
                              void* d_out, int out_size, void* d_ws, size_t ws_size,
                              hipStream_t stream) {
  const float* x = (const float*)d_in[0];
  const float* qkv_w = (const float*)d_in[1];
  const float* qkv_b = (const float*)d_in[2];
  const float* dw_w = (const float*)d_in[3];
  const float* dw_b = (const float*)d_in[4];
  const float* proj_w = (const float*)d_in[5];
  const float* proj_b = (const float*)d_in[6];
  const float* temp = (const float*)d_in[7];

  const size_t SZ_XT = (size_t)BATCH * HW * DIM * 2;      // 100,663,296 (also vT)
  const size_t SZ_C1 = (size_t)BATCH * C3 * HW * 2;       // 301,989,888
  const size_t SZ_WQB = (size_t)C3 * DIM * 2;             // 884,736
  const size_t SZ_SQ = (size_t)BATCH * 2 * DIM * 4;       // 24,576
  const size_t SZ_G = (size_t)BATCH * HEADS * CH * CH * 4;  // 589,824

  const size_t OFF_XT = 0;
  const size_t OFF_C1 = OFF_XT + SZ_XT;
  const size_t OFF_QKVD = OFF_C1 + SZ_C1;
  const size_t OFF_WQB = OFF_QKVD + SZ_C1;
  const size_t OFF_SQ = OFF_WQB + SZ_WQB;
  const size_t OFF_G = OFF_SQ + SZ_SQ;
  const size_t OFF_ATTN = OFF_G + SZ_G;
  const size_t OFF_WEFF = OFF_ATTN + SZ_G;
  const size_t TOTAL = OFF_WEFF + (size_t)BATCH * DIM * DIM * 2;
  if (ws_size < TOTAL) return;  // fail loudly (validation) rather than corrupt

  char* ws = (char*)d_ws;
  ushort* xT = (ushort*)(ws + OFF_XT);   // later reused as vT
  ushort* c1 = (ushort*)(ws + OFF_C1);
  ushort* qkvd = (ushort*)(ws + OFF_QKVD);
  ushort* wqb = (ushort*)(ws + OFF_WQB);
  float* sq = (float*)(ws + OFF_SQ);
  float* G = (float*)(ws + OFF_G);
  float* attn = (float*)(ws + OFF_ATTN);
  ushort* weff = (ushort*)(ws + OFF_WEFF);

  hipMemsetAsync(ws + OFF_SQ, 0, SZ_SQ + SZ_G, stream);

  cast_w<<<(C3 * DIM) / 1024, 256, 0, stream>>>(qkv_w, wqb, C3 * DIM);
  transpose_cast<float><<<dim3(HW / 64, DIM / 64, BATCH), 256, 0, stream>>>(
      x, xT, DIM, HW, (long)DIM * HW, (long)HW * DIM);
  gemm_nt<1><<<dim3(C3 / 128, HW / 128, BATCH), 256, 0, stream>>>(
      wqb, xT, qkv_b, (void*)c1, C3, HW, DIM, 0L, (long)HW * DIM, (long)C3 * HW);
  dwconv<<<dim3(C3, BATCH), 256, 0, stream>>>(c1, dw_w, dw_b, qkvd, sq);
  gram<<<dim3(16, BATCH * HEADS), 256, 0, stream>>>(qkvd, G);
  softmax_k<<<BATCH * HEADS, 64, 0, stream>>>(G, sq, temp, attn);
  weff_k<<<dim3(DIM, BATCH), 384, 0, stream>>>(proj_w, attn, weff);
  // transpose v (bf16) into the xT region (xT is dead after K1)
  transpose_cast<ushort><<<dim3(HW / 64, DIM / 64, BATCH), 256, 0, stream>>>(
      qkvd + (size_t)2 * DIM * HW, xT, DIM, HW, (long)C3 * HW, (long)HW * DIM);
  gemm_nt<0><<<dim3(DIM / 128, HW / 128, BATCH), 256, 0, stream>>>(
      weff, xT, proj_b, d_out, DIM, HW, DIM, (long)DIM * DIM, (long)HW * DIM,
      (long)DIM * HW);
}

// Round 5
// 543.506 us; speedup vs baseline: 1.6295x; 1.2370x over previous
//
#include <hip/hip_runtime.h>
#include <hip/hip_bf16.h>
#include <cstdint>

// ---------------------------------------------------------------------------
// XCA attention: qkv 1x1 conv -> dw3x3 -> l2norm -> 48x48 channel attn -> proj
//   KW  cast qkv_w -> bf16
//   K1  gemm_px<float,1>: qkv = W(1152x384) @ x   (persistent pixel-panel,
//       fused x transpose+cast, A via swizzled global_load_lds)
//   K2  depthwise 3x3 + bias (register-streaming), fused sumsq
//   K2b Gram G[b,h] = q @ k^T (unnormalized, MFMA direct-from-global, split-K)
//   K3a logits = temp * G / (|q||k|) -> softmax -> attn
//   K3b W_eff[b] = proj_w @ blockdiag(attn)   (384x384 per batch)
//   K4  gemm_px<ushort,0>: out = W_eff @ v + proj_b (fused v transpose)
// ---------------------------------------------------------------------------

#define BATCH 8
#define DIM 384
#define HEADS 8
#define CH 48           // DIM/HEADS
#define HW 16384
#define C3 1152         // 3*DIM

typedef __attribute__((ext_vector_type(8))) short bf16x8;
typedef __attribute__((ext_vector_type(8))) unsigned short u16x8;
typedef __attribute__((ext_vector_type(4))) float f32x4;

__device__ __forceinline__ float b2f(ushort b) {
  union { float f; unsigned u; } x; x.u = ((unsigned)b) << 16; return x.f;
}
__device__ __forceinline__ ushort f2b(float f) {
  union { float f; unsigned u; } x; x.f = f;
  unsigned r = x.u + 0x7fffu + ((x.u >> 16) & 1u);
  return (ushort)(r >> 16);
}

// async global->LDS, 16B per lane. LDS dest = wave-uniform base + lane*16.
__device__ __forceinline__ void async16(const ushort* g, ushort* l) {
  __builtin_amdgcn_global_load_lds(
      (const __attribute__((address_space(1))) unsigned int*)(unsigned long long)(uintptr_t)g,
      (__attribute__((address_space(3))) unsigned int*)(unsigned int)(uintptr_t)l,
      16, 0, 0);
}

// ---------------- KW: cast weights to bf16 ----------------------------------
__global__ __launch_bounds__(256) void cast_w(const float* __restrict__ s,
                                              ushort* __restrict__ d, int n) {
  int i = (blockIdx.x * 256 + threadIdx.x) * 4;
  if (i + 3 < n) {
    float4 v = *(const float4*)(s + i);
    ushort4 o = make_ushort4(f2b(v.x), f2b(v.y), f2b(v.z), f2b(v.w));
    *(ushort4*)(d + i) = o;
  }
}

// ---------------- K1/K4: persistent pixel-panel GEMM ------------------------
// Block = (128-pixel panel, batch). Out[b][gr][pix] = sum_c A[gr][c]*src[b][c][pix].
// B panel (128 pix x 384 chans, transposed+cast from src) loaded ONCE into
// Bs[pix][c] pitch 392 (bank-optimal b128 reads). A tiles (128x64) staged via
// global_load_lds with XOR-swizzled SOURCE (LDS linear, m173 pattern) so frag
// reads are bank-optimal. 512 threads = 8 waves (4M x 2N), 2-phase A dbuf.
template <typename SrcT, int OUT_BF16>
__global__ __launch_bounds__(512) void gemm_px(
    const ushort* __restrict__ A, const SrcT* __restrict__ src,
    const float* __restrict__ bias, void* __restrict__ Cout,
    int M, long Asb, long Ssb, long Csb) {
  constexpr int K = DIM;   // 384
  constexpr int BP = 392;  // Bs pitch (u16): bank step 4 -> 8-beat-optimal reads
  int zb = blockIdx.y;
  int px0 = blockIdx.x * 128;
  const ushort* Ab = A + (size_t)zb * Asb;
  const SrcT* Sb = src + (size_t)zb * Ssb;
  __shared__ __align__(16) ushort Bs[128 * BP];      // 100,352 B
  __shared__ __align__(16) ushort As[2][128 * 64];   // 32,768 B
  int tid = threadIdx.x, lane = tid & 63, wid = tid >> 6;
  int wm = wid >> 1, wn = wid & 1;
  int fr = lane & 15, fs = lane >> 4;

  // ---- B panel load: lane-transposed global read (coalesced per chan-row),
  //      one ds_write_b128 per 8 chans.
  {
    int pix = tid & 127;
    int cg = tid >> 7;  // 0..3
#pragma unroll
    for (int rr = 0; rr < 12; ++rr) {
      int c8 = cg + rr * 4;  // 0..47
      u16x8 pk;
#pragma unroll
      for (int j = 0; j < 8; ++j) {
        int c = c8 * 8 + j;
        if constexpr (sizeof(SrcT) == 4)
          pk[j] = f2b(((const float*)Sb)[(size_t)c * HW + px0 + pix]);
        else
          pk[j] = ((const ushort*)Sb)[(size_t)c * HW + px0 + pix];
      }
      *(u16x8*)&Bs[pix * BP + c8 * 8] = pk;
    }
  }

  auto stageA = [&](int buf, int mt, int k0) {
#pragma unroll
    for (int q = 0; q < 2; ++q) {
      int r = q * 64 + wid * 8 + (lane >> 3);
      int col = ((lane & 7) ^ (r & 7)) * 8;  // pre-swizzled source slot
      async16(Ab + (size_t)(mt * 128 + r) * K + k0 + col,
              &As[buf][(q * 64 + wid * 8) * 64]);
    }
  };

  f32x4 acc[2][4];
  auto compute = [&](int buf, int k0) {
#pragma unroll
    for (int kk = 0; kk < 2; ++kk) {
      bf16x8 af[2], bv[4];
#pragma unroll
      for (int m = 0; m < 2; ++m) {
        int R = wm * 32 + m * 16 + fr;
        int slot = kk * 4 + fs;
        af[m] = *(const bf16x8*)&As[buf][R * 64 + ((slot ^ (R & 7)) << 3)];
      }
#pragma unroll
      for (int n = 0; n < 4; ++n) {
        int P = wn * 64 + n * 16 + fr;
        bv[n] = *(const bf16x8*)&Bs[P * BP + k0 + kk * 32 + (fs << 3)];
      }
#pragma unroll
      for (int m = 0; m < 2; ++m)
#pragma unroll
        for (int n = 0; n < 4; ++n)
          acc[m][n] = __builtin_amdgcn_mfma_f32_16x16x32_bf16(af[m], bv[n], acc[m][n], 0, 0, 0);
    }
  };

  const int MT = M >> 7;
  stageA(0, 0, 0);
  __syncthreads();  // Bs + first A tile ready

  for (int mt = 0; mt < MT; ++mt) {
    f32x4 zero = {0.f, 0.f, 0.f, 0.f};
#pragma unroll
    for (int m = 0; m < 2; ++m)
#pragma unroll
      for (int n = 0; n < 4; ++n) acc[m][n] = zero;
#pragma unroll
    for (int t = 0; t < 5; ++t) {
      stageA((t + 1) & 1, mt, (t + 1) * 64);  // prefetch next k-tile
      __builtin_amdgcn_s_setprio(1);
      compute(t & 1, t * 64);
      __builtin_amdgcn_s_setprio(0);
      __syncthreads();
    }
    if (mt + 1 < MT) stageA(0, mt + 1, 0);  // prefetch next m-tile's first k
    __builtin_amdgcn_s_setprio(1);
    compute(1, 320);
    __builtin_amdgcn_s_setprio(0);
    // epilogue for this m-tile (C/D layout: row = fs*4+j, col = fr)
#pragma unroll
    for (int m = 0; m < 2; ++m)
#pragma unroll
      for (int j = 0; j < 4; ++j) {
        int gr = mt * 128 + wm * 32 + m * 16 + fs * 4 + j;
        float bz = bias[gr];
#pragma unroll
        for (int n = 0; n < 4; ++n) {
          int gc = px0 + wn * 64 + n * 16 + fr;
          float v = acc[m][n][j] + bz;
          if constexpr (OUT_BF16)
            ((ushort*)Cout)[(size_t)zb * Csb + (size_t)gr * HW + gc] = f2b(v);
          else
            ((float*)Cout)[(size_t)zb * Csb + (size_t)gr * HW + gc] = v;
        }
      }
    __syncthreads();  // drain prefetch; protect As[1] before next mt's t=0 stage
  }
}

// ---------------- K2: depthwise 3x3 + bias + sumsq (register streaming) -----
__global__ __launch_bounds__(256) void dwconv(
    const ushort* __restrict__ in, const float* __restrict__ w9,
    const float* __restrict__ b9, ushort* __restrict__ out,
    float* __restrict__ sq) {
  int ch = blockIdx.x;   // 0..1151
  int b = blockIdx.y;
  const size_t plane = ((size_t)b * C3 + ch) * HW;
  int tid = threadIdx.x, lane = tid & 63;
  int rg = tid >> 4, cg = tid & 15;
  int r0 = rg * 8, c0 = cg * 8;

  float w[9];
#pragma unroll
  for (int i = 0; i < 9; ++i) w[i] = w9[ch * 9 + i];
  float bias = b9[ch];

  float a0[8], a1[8];
#pragma unroll
  for (int c = 0; c < 8; ++c) { a0[c] = 0.f; a1[c] = 0.f; }
  float ss = 0.f;

#pragma unroll
  for (int it = 0; it < 10; ++it) {
    int r = r0 - 1 + it;
    float x[8];
    if ((unsigned)r < 128u) {
      u16x8 raw = *(const u16x8*)(in + plane + (size_t)r * 128 + c0);
#pragma unroll
      for (int c = 0; c < 8; ++c) x[c] = b2f(raw[c]);
    } else {
#pragma unroll
      for (int c = 0; c < 8; ++c) x[c] = 0.f;
    }
    float xl = __shfl(x[7], lane - 1);
    float xr = __shfl(x[0], lane + 1);
    if (cg == 0) xl = 0.f;
    if (cg == 15) xr = 0.f;

    float h0[8], h1[8], h2[8];
#pragma unroll
    for (int c = 0; c < 8; ++c) {
      float l = (c == 0) ? xl : x[c - 1];
      float rt = (c == 7) ? xr : x[c + 1];
      h0[c] = w[0] * l + w[1] * x[c] + w[2] * rt;
      h1[c] = w[3] * l + w[4] * x[c] + w[5] * rt;
      h2[c] = w[6] * l + w[7] * x[c] + w[8] * rt;
    }
    if (it >= 2) {
      int R = r - 1;  // output row, in [r0, r0+7]
      u16x8 pk;
#pragma unroll
      for (int c = 0; c < 8; ++c) {
        float o = a0[c] + h2[c] + bias;
        ss += o * o;
        pk[c] = f2b(o);
      }
      *(u16x8*)(out + plane + (size_t)R * 128 + c0) = pk;
    }
#pragma unroll
    for (int c = 0; c < 8; ++c) { a0[c] = a1[c] + h1[c]; a1[c] = h0[c]; }
  }

  if (ch < 2 * DIM) {
#pragma unroll
    for (int off = 32; off; off >>= 1) ss += __shfl_down(ss, off, 64);
    if (lane == 0) atomicAdd(&sq[b * 2 * DIM + ch], ss);
  }
}

// ---------------- K2b: unnormalized Gram G[b,h] = q @ k^T -------------------
__global__ __launch_bounds__(256) void gram(const ushort* __restrict__ qkvd,
                                            float* __restrict__ G) {
  int chunk = blockIdx.x;  // 0..15 (split-K over pixels)
  int bh = blockIdx.y;     // 0..63
  int b = bh >> 3, h = bh & 7;
  int tid = threadIdx.x, lane = tid & 63, wid = tid >> 6;
  const ushort* qbase = qkvd + ((size_t)b * C3 + h * CH) * HW;
  const ushort* kbase = qbase + (size_t)DIM * HW;
  int pix0 = chunk * 1024 + wid * 256;
  int fr = lane & 15, fk = (lane >> 4) * 8;
  f32x4 zero = {0.f, 0.f, 0.f, 0.f};
  f32x4 acc[3][3];
#pragma unroll
  for (int i = 0; i < 3; ++i)
#pragma unroll
    for (int j = 0; j < 3; ++j) acc[i][j] = zero;
#pragma unroll
  for (int it = 0; it < 8; ++it) {
    int pix = pix0 + it * 32 + fk;
    bf16x8 aq[3], bk[3];
#pragma unroll
    for (int mi = 0; mi < 3; ++mi)
      aq[mi] = *(const bf16x8*)(qbase + (size_t)(mi * 16 + fr) * HW + pix);
#pragma unroll
    for (int ni = 0; ni < 3; ++ni)
      bk[ni] = *(const bf16x8*)(kbase + (size_t)(ni * 16 + fr) * HW + pix);
#pragma unroll
    for (int mi = 0; mi < 3; ++mi)
#pragma unroll
      for (int ni = 0; ni < 3; ++ni)
        acc[mi][ni] = __builtin_amdgcn_mfma_f32_16x16x32_bf16(aq[mi], bk[ni], acc[mi][ni], 0, 0, 0);
  }
  __shared__ float gs[CH * CH];
  for (int i = tid; i < CH * CH; i += 256) gs[i] = 0.f;
  __syncthreads();
  int crow = (lane >> 4) * 4, ccol = lane & 15;
#pragma unroll
  for (int mi = 0; mi < 3; ++mi)
#pragma unroll
    for (int ni = 0; ni < 3; ++ni)
#pragma unroll
      for (int j = 0; j < 4; ++j)
        atomicAdd(&gs[(mi * 16 + crow + j) * CH + ni * 16 + ccol], acc[mi][ni][j]);
  __syncthreads();
  float* Gp = G + (size_t)bh * CH * CH;
  for (int i = tid; i < CH * CH; i += 256) atomicAdd(&Gp[i], gs[i]);
}

// ---------------- K3a: normalize + softmax ----------------------------------
__global__ void softmax_k(const float* __restrict__ G, const float* __restrict__ sq,
                          const float* __restrict__ temp, float* __restrict__ attn) {
  int bh = blockIdx.x, b = bh >> 3, h = bh & 7;
  int lane = threadIdx.x;
  __shared__ float inq[CH], ink[CH];
  if (lane < CH) {
    inq[lane] = 1.f / fmaxf(sqrtf(sq[b * 2 * DIM + h * CH + lane]), 1e-12f);
    ink[lane] = 1.f / fmaxf(sqrtf(sq[b * 2 * DIM + DIM + h * CH + lane]), 1e-12f);
  }
  __syncthreads();
  if (lane < CH) {
    float t = temp[h] * inq[lane];
    const float* g = G + (size_t)bh * CH * CH + lane * CH;
    float v[CH];
    float mx = -1e30f;
#pragma unroll
    for (int d = 0; d < CH; ++d) { v[d] = t * g[d] * ink[d]; mx = fmaxf(mx, v[d]); }
    float s = 0.f;
#pragma unroll
    for (int d = 0; d < CH; ++d) { v[d] = expf(v[d] - mx); s += v[d]; }
    float inv = 1.f / s;
    float* a = attn + (size_t)bh * CH * CH + lane * CH;
#pragma unroll
    for (int d = 0; d < CH; ++d) a[d] = v[d] * inv;
  }
}

// ---------------- K3b: W_eff[b] = proj_w @ blockdiag(attn) ------------------
__global__ __launch_bounds__(384) void weff_k(const float* __restrict__ pw,
                                              const float* __restrict__ attn,
                                              ushort* __restrict__ weff) {
  int dg = threadIdx.x;  // 0..383
  int p = blockIdx.x;    // 0..383
  int b = blockIdx.y;
  int h = dg / CH, d = dg - h * CH;
  const float* a = attn + (((size_t)b * HEADS + h) * CH) * CH + d;
  const float* wrow = pw + (size_t)p * DIM + h * CH;
  float s = 0.f;
#pragma unroll
  for (int c = 0; c < CH; ++c) s += wrow[c] * a[c * CH];
  weff[((size_t)b * DIM + p) * DIM + dg] = f2b(s);
}

// ---------------------------------------------------------------------------
extern "C" void kernel_launch(void* const* d_in, const int* in_sizes, int n_in,
                              void* d_out, int out_size, void* d_ws, size_t ws_size,
                              hipStream_t stream) {
  const float* x = (const float*)d_in[0];
  const float* qkv_w = (const float*)d_in[1];
  const float* qkv_b = (const float*)d_in[2];
  const float* dw_w = (const float*)d_in[3];
  const float* dw_b = (const float*)d_in[4];
  const float* proj_w = (const float*)d_in[5];
  const float* proj_b = (const float*)d_in[6];
  const float* temp = (const float*)d_in[7];

  const size_t SZ_C1 = (size_t)BATCH * C3 * HW * 2;       // 301,989,888
  const size_t SZ_WQB = (size_t)C3 * DIM * 2;             // 884,736
  const size_t SZ_SQ = (size_t)BATCH * 2 * DIM * 4;       // 24,576
  const size_t SZ_G = (size_t)BATCH * HEADS * CH * CH * 4;  // 589,824

  const size_t OFF_C1 = 0;
  const size_t OFF_QKVD = OFF_C1 + SZ_C1;
  const size_t OFF_WQB = OFF_QKVD + SZ_C1;
  const size_t OFF_SQ = OFF_WQB + SZ_WQB;
  const size_t OFF_G = OFF_SQ + SZ_SQ;
  const size_t OFF_ATTN = OFF_G + SZ_G;
  const size_t OFF_WEFF = OFF_ATTN + SZ_G;
  const size_t TOTAL = OFF_WEFF + (size_t)BATCH * DIM * DIM * 2;
  if (ws_size < TOTAL) return;  // fail loudly (validation) rather than corrupt

  char* ws = (char*)d_ws;
  ushort* c1 = (ushort*)(ws + OFF_C1);
  ushort* qkvd = (ushort*)(ws + OFF_QKVD);
  ushort* wqb = (ushort*)(ws + OFF_WQB);
  float* sq = (float*)(ws + OFF_SQ);
  float* G = (float*)(ws + OFF_G);
  float* attn = (float*)(ws + OFF_ATTN);
  ushort* weff = (ushort*)(ws + OFF_WEFF);

  hipMemsetAsync(ws + OFF_SQ, 0, SZ_SQ + SZ_G, stream);

  cast_w<<<(C3 * DIM) / 1024, 256, 0, stream>>>(qkv_w, wqb, C3 * DIM);
  // K1: qkv = wqb @ x (+bias), fused x transpose+cast, bf16 out
  gemm_px<float, 1><<<dim3(HW / 128, BATCH), 512, 0, stream>>>(
      wqb, x, qkv_b, (void*)c1, C3, 0L, (long)DIM * HW, (long)C3 * HW);
  dwconv<<<dim3(C3, BATCH), 256, 0, stream>>>(c1, dw_w, dw_b, qkvd, sq);
  gram<<<dim3(16, BATCH * HEADS), 256, 0, stream>>>(qkvd, G);
  softmax_k<<<BATCH * HEADS, 64, 0, stream>>>(G, sq, temp, attn);
  weff_k<<<dim3(DIM, BATCH), 384, 0, stream>>>(proj_w, attn, weff);
  // K4: out = weff @ v (+proj_b), fused v transpose, f32 out
  gemm_px<ushort, 0><<<dim3(HW / 128, BATCH), 512, 0, stream>>>(
      weff, qkvd + (size_t)2 * DIM * HW, proj_b, d_out, DIM,
      (long)DIM * DIM, (long)C3 * HW, (long)DIM * HW);
}

// Round 6
// 534.323 us; speedup vs baseline: 1.6575x; 1.0172x over previous
//
#include <hip/hip_runtime.h>
#include <hip/hip_bf16.h>
#include <cstdint>

// ---------------------------------------------------------------------------
// XCA attention: qkv 1x1 conv -> dw3x3 -> l2norm -> 48x48 channel attn -> proj
//   KW  cast qkv_w -> bf16
//   K1  gemm_px<float,1>: qkv = W(1152x384) @ x   (persistent 64-px panel,
//       fused x transpose+cast, 2 blocks/CU, XOR-swizzled LDS)
//   K2  depthwise 3x3 + bias (register-streaming), fused sumsq
//   K2b Gram G[b,h] = q @ k^T (unnormalized, MFMA direct-from-global, split-K)
//   K3a logits = temp * G / (|q||k|) -> softmax -> attn
//   K3b W_eff[b] = proj_w @ blockdiag(attn)   (384x384 per batch)
//   K4  gemm_px<ushort,0>: out = W_eff @ v + proj_b (fused v transpose)
// ---------------------------------------------------------------------------

#define BATCH 8
#define DIM 384
#define HEADS 8
#define CH 48           // DIM/HEADS
#define HW 16384
#define C3 1152         // 3*DIM

typedef __attribute__((ext_vector_type(8))) short bf16x8;
typedef __attribute__((ext_vector_type(8))) unsigned short u16x8;
typedef __attribute__((ext_vector_type(4))) float f32x4;

__device__ __forceinline__ float b2f(ushort b) {
  union { float f; unsigned u; } x; x.u = ((unsigned)b) << 16; return x.f;
}
__device__ __forceinline__ ushort f2b(float f) {
  union { float f; unsigned u; } x; x.f = f;
  unsigned r = x.u + 0x7fffu + ((x.u >> 16) & 1u);
  return (ushort)(r >> 16);
}

// async global->LDS, 16B per lane. LDS dest = wave-uniform base + lane*16.
__device__ __forceinline__ void async16(const ushort* g, ushort* l) {
  __builtin_amdgcn_global_load_lds(
      (const __attribute__((address_space(1))) unsigned int*)(unsigned long long)(uintptr_t)g,
      (__attribute__((address_space(3))) unsigned int*)(unsigned int)(uintptr_t)l,
      16, 0, 0);
}

// ---------------- KW: cast weights to bf16 ----------------------------------
__global__ __launch_bounds__(256) void cast_w(const float* __restrict__ s,
                                              ushort* __restrict__ d, int n) {
  int i = (blockIdx.x * 256 + threadIdx.x) * 4;
  if (i + 3 < n) {
    float4 v = *(const float4*)(s + i);
    ushort4 o = make_ushort4(f2b(v.x), f2b(v.y), f2b(v.z), f2b(v.w));
    *(ushort4*)(d + i) = o;
  }
}

// ---------------- K1/K4: persistent pixel-panel GEMM, 2 blocks/CU -----------
// Block = (64-pixel panel, batch). Out[b][gr][pix] = sum_c A[gr][c]*src[b][c][pix].
// B panel (64 px x 384 ch, transposed+cast from src) loaded ONCE into
// Bs[pix][384], k-slot XOR-swizzled by (pix&7) -> bank-minimal b128 on both
// write and read. A tiles (128x64) staged via global_load_lds, XOR-swizzled
// SOURCE (LDS linear, m173 pattern). 256 threads = 4 waves (2M x 2N), wave
// tile 64 rows x 32 px (4 m-frags x 2 n-frags). LDS = 80 KB exactly ->
// 2 independent blocks/CU (barrier decoupling: one computes while the other
// panel-loads / drains).
template <typename SrcT, int OUT_BF16>
__global__ __launch_bounds__(256, 2) void gemm_px(
    const ushort* __restrict__ A, const SrcT* __restrict__ src,
    const float* __restrict__ bias, void* __restrict__ Cout,
    int M, long Asb, long Ssb, long Csb) {
  constexpr int K = DIM;  // 384
  int zb = blockIdx.y;
  int px0 = blockIdx.x * 64;
  const ushort* Ab = A + (size_t)zb * Asb;
  const SrcT* Sb = src + (size_t)zb * Ssb;
  __shared__ __align__(16) ushort Bs[64 * 384];     // 49,152 B
  __shared__ __align__(16) ushort As[2][128 * 64];  // 32,768 B
  int tid = threadIdx.x, lane = tid & 63, wid = tid >> 6;
  int wm = wid >> 1, wn = wid & 1;
  int fr = lane & 15, fs = lane >> 4;

  // ---- B panel load: lane-coalesced global read, swizzled ds_write_b128.
  {
    int pix = tid & 63;
    int cg = tid >> 6;  // 0..3
#pragma unroll
    for (int rr = 0; rr < 12; ++rr) {
      int c8 = cg + rr * 4;  // k-slot 0..47
      u16x8 pk;
#pragma unroll
      for (int j = 0; j < 8; ++j) {
        int c = c8 * 8 + j;
        if constexpr (sizeof(SrcT) == 4)
          pk[j] = f2b(((const float*)Sb)[(size_t)c * HW + px0 + pix]);
        else
          pk[j] = ((const ushort*)Sb)[(size_t)c * HW + px0 + pix];
      }
      *(u16x8*)&Bs[pix * 384 + ((c8 ^ (pix & 7)) << 3)] = pk;
    }
  }

  auto stageA = [&](int buf, int mt, int k0) {
#pragma unroll
    for (int q = 0; q < 4; ++q) {
      int r = q * 32 + wid * 8 + (lane >> 3);
      int col = ((lane & 7) ^ (r & 7)) * 8;  // pre-swizzled source slot
      async16(Ab + (size_t)(mt * 128 + r) * K + k0 + col,
              &As[buf][(q * 32 + wid * 8) * 64]);
    }
  };

  f32x4 acc[4][2];
  auto compute = [&](int buf, int k0) {
#pragma unroll
    for (int kk = 0; kk < 2; ++kk) {
      bf16x8 af[4], bv[2];
#pragma unroll
      for (int m = 0; m < 4; ++m) {
        int R = wm * 64 + m * 16 + fr;
        int slot = kk * 4 + fs;  // tile-local k-slot 0..7
        af[m] = *(const bf16x8*)&As[buf][R * 64 + ((slot ^ (R & 7)) << 3)];
      }
#pragma unroll
      for (int n = 0; n < 2; ++n) {
        int P = wn * 32 + n * 16 + fr;
        int gslot = (k0 >> 3) + kk * 4 + fs;  // global k-slot 0..47
        bv[n] = *(const bf16x8*)&Bs[P * 384 + ((gslot ^ (P & 7)) << 3)];
      }
#pragma unroll
      for (int m = 0; m < 4; ++m)
#pragma unroll
        for (int n = 0; n < 2; ++n)
          acc[m][n] = __builtin_amdgcn_mfma_f32_16x16x32_bf16(af[m], bv[n], acc[m][n], 0, 0, 0);
    }
  };

  const int MT = M >> 7;
  stageA(0, 0, 0);
  __syncthreads();  // Bs + first A tile ready

  for (int mt = 0; mt < MT; ++mt) {
    f32x4 zero = {0.f, 0.f, 0.f, 0.f};
#pragma unroll
    for (int m = 0; m < 4; ++m)
#pragma unroll
      for (int n = 0; n < 2; ++n) acc[m][n] = zero;
#pragma unroll
    for (int t = 0; t < 5; ++t) {
      stageA((t + 1) & 1, mt, (t + 1) * 64);  // prefetch next k-tile
      __builtin_amdgcn_s_setprio(1);
      compute(t & 1, t * 64);
      __builtin_amdgcn_s_setprio(0);
      __syncthreads();
    }
    if (mt + 1 < MT) stageA(0, mt + 1, 0);  // prefetch next m-tile's first k
    __builtin_amdgcn_s_setprio(1);
    compute(1, 320);
    __builtin_amdgcn_s_setprio(0);
    // epilogue (C/D layout: row = fs*4+j, col = fr)
#pragma unroll
    for (int m = 0; m < 4; ++m)
#pragma unroll
      for (int j = 0; j < 4; ++j) {
        int gr = mt * 128 + wm * 64 + m * 16 + fs * 4 + j;
        float bz = bias[gr];
#pragma unroll
        for (int n = 0; n < 2; ++n) {
          int gc = px0 + wn * 32 + n * 16 + fr;
          float v = acc[m][n][j] + bz;
          if constexpr (OUT_BF16)
            ((ushort*)Cout)[(size_t)zb * Csb + (size_t)gr * HW + gc] = f2b(v);
          else
            ((float*)Cout)[(size_t)zb * Csb + (size_t)gr * HW + gc] = v;
        }
      }
    __syncthreads();  // drain prefetch; protect buffers before next mt
  }
}

// ---------------- K2: depthwise 3x3 + bias + sumsq (register streaming) -----
__global__ __launch_bounds__(256) void dwconv(
    const ushort* __restrict__ in, const float* __restrict__ w9,
    const float* __restrict__ b9, ushort* __restrict__ out,
    float* __restrict__ sq) {
  int ch = blockIdx.x;   // 0..1151
  int b = blockIdx.y;
  const size_t plane = ((size_t)b * C3 + ch) * HW;
  int tid = threadIdx.x, lane = tid & 63;
  int rg = tid >> 4, cg = tid & 15;
  int r0 = rg * 8, c0 = cg * 8;

  float w[9];
#pragma unroll
  for (int i = 0; i < 9; ++i) w[i] = w9[ch * 9 + i];
  float bias = b9[ch];

  float a0[8], a1[8];
#pragma unroll
  for (int c = 0; c < 8; ++c) { a0[c] = 0.f; a1[c] = 0.f; }
  float ss = 0.f;

#pragma unroll
  for (int it = 0; it < 10; ++it) {
    int r = r0 - 1 + it;
    float x[8];
    if ((unsigned)r < 128u) {
      u16x8 raw = *(const u16x8*)(in + plane + (size_t)r * 128 + c0);
#pragma unroll
      for (int c = 0; c < 8; ++c) x[c] = b2f(raw[c]);
    } else {
#pragma unroll
      for (int c = 0; c < 8; ++c) x[c] = 0.f;
    }
    float xl = __shfl(x[7], lane - 1);
    float xr = __shfl(x[0], lane + 1);
    if (cg == 0) xl = 0.f;
    if (cg == 15) xr = 0.f;

    float h0[8], h1[8], h2[8];
#pragma unroll
    for (int c = 0; c < 8; ++c) {
      float l = (c == 0) ? xl : x[c - 1];
      float rt = (c == 7) ? xr : x[c + 1];
      h0[c] = w[0] * l + w[1] * x[c] + w[2] * rt;
      h1[c] = w[3] * l + w[4] * x[c] + w[5] * rt;
      h2[c] = w[6] * l + w[7] * x[c] + w[8] * rt;
    }
    if (it >= 2) {
      int R = r - 1;  // output row, in [r0, r0+7]
      u16x8 pk;
#pragma unroll
      for (int c = 0; c < 8; ++c) {
        float o = a0[c] + h2[c] + bias;
        ss += o * o;
        pk[c] = f2b(o);
      }
      *(u16x8*)(out + plane + (size_t)R * 128 + c0) = pk;
    }
#pragma unroll
    for (int c = 0; c < 8; ++c) { a0[c] = a1[c] + h1[c]; a1[c] = h0[c]; }
  }

  if (ch < 2 * DIM) {
#pragma unroll
    for (int off = 32; off; off >>= 1) ss += __shfl_down(ss, off, 64);
    if (lane == 0) atomicAdd(&sq[b * 2 * DIM + ch], ss);
  }
}

// ---------------- K2b: unnormalized Gram G[b,h] = q @ k^T -------------------
__global__ __launch_bounds__(256) void gram(const ushort* __restrict__ qkvd,
                                            float* __restrict__ G) {
  int chunk = blockIdx.x;  // 0..15 (split-K over pixels)
  int bh = blockIdx.y;     // 0..63
  int b = bh >> 3, h = bh & 7;
  int tid = threadIdx.x, lane = tid & 63, wid = tid >> 6;
  const ushort* qbase = qkvd + ((size_t)b * C3 + h * CH) * HW;
  const ushort* kbase = qbase + (size_t)DIM * HW;
  int pix0 = chunk * 1024 + wid * 256;
  int fr = lane & 15, fk = (lane >> 4) * 8;
  f32x4 zero = {0.f, 0.f, 0.f, 0.f};
  f32x4 acc[3][3];
#pragma unroll
  for (int i = 0; i < 3; ++i)
#pragma unroll
    for (int j = 0; j < 3; ++j) acc[i][j] = zero;
#pragma unroll
  for (int it = 0; it < 8; ++it) {
    int pix = pix0 + it * 32 + fk;
    bf16x8 aq[3], bk[3];
#pragma unroll
    for (int mi = 0; mi < 3; ++mi)
      aq[mi] = *(const bf16x8*)(qbase + (size_t)(mi * 16 + fr) * HW + pix);
#pragma unroll
    for (int ni = 0; ni < 3; ++ni)
      bk[ni] = *(const bf16x8*)(kbase + (size_t)(ni * 16 + fr) * HW + pix);
#pragma unroll
    for (int mi = 0; mi < 3; ++mi)
#pragma unroll
      for (int ni = 0; ni < 3; ++ni)
        acc[mi][ni] = __builtin_amdgcn_mfma_f32_16x16x32_bf16(aq[mi], bk[ni], acc[mi][ni], 0, 0, 0);
  }
  __shared__ float gs[CH * CH];
  for (int i = tid; i < CH * CH; i += 256) gs[i] = 0.f;
  __syncthreads();
  int crow = (lane >> 4) * 4, ccol = lane & 15;
#pragma unroll
  for (int mi = 0; mi < 3; ++mi)
#pragma unroll
    for (int ni = 0; ni < 3; ++ni)
#pragma unroll
      for (int j = 0; j < 4; ++j)
        atomicAdd(&gs[(mi * 16 + crow + j) * CH + ni * 16 + ccol], acc[mi][ni][j]);
  __syncthreads();
  float* Gp = G + (size_t)bh * CH * CH;
  for (int i = tid; i < CH * CH; i += 256) atomicAdd(&Gp[i], gs[i]);
}

// ---------------- K3a: normalize + softmax ----------------------------------
__global__ void softmax_k(const float* __restrict__ G, const float* __restrict__ sq,
                          const float* __restrict__ temp, float* __restrict__ attn) {
  int bh = blockIdx.x, b = bh >> 3, h = bh & 7;
  int lane = threadIdx.x;
  __shared__ float inq[CH], ink[CH];
  if (lane < CH) {
    inq[lane] = 1.f / fmaxf(sqrtf(sq[b * 2 * DIM + h * CH + lane]), 1e-12f);
    ink[lane] = 1.f / fmaxf(sqrtf(sq[b * 2 * DIM + DIM + h * CH + lane]), 1e-12f);
  }
  __syncthreads();
  if (lane < CH) {
    float t = temp[h] * inq[lane];
    const float* g = G + (size_t)bh * CH * CH + lane * CH;
    float v[CH];
    float mx = -1e30f;
#pragma unroll
    for (int d = 0; d < CH; ++d) { v[d] = t * g[d] * ink[d]; mx = fmaxf(mx, v[d]); }
    float s = 0.f;
#pragma unroll
    for (int d = 0; d < CH; ++d) { v[d] = expf(v[d] - mx); s += v[d]; }
    float inv = 1.f / s;
    float* a = attn + (size_t)bh * CH * CH + lane * CH;
#pragma unroll
    for (int d = 0; d < CH; ++d) a[d] = v[d] * inv;
  }
}

// ---------------- K3b: W_eff[b] = proj_w @ blockdiag(attn) ------------------
__global__ __launch_bounds__(384) void weff_k(const float* __restrict__ pw,
                                              const float* __restrict__ attn,
                                              ushort* __restrict__ weff) {
  int dg = threadIdx.x;  // 0..383
  int p = blockIdx.x;    // 0..383
  int b = blockIdx.y;
  int h = dg / CH, d = dg - h * CH;
  const float* a = attn + (((size_t)b * HEADS + h) * CH) * CH + d;
  const float* wrow = pw + (size_t)p * DIM + h * CH;
  float s = 0.f;
#pragma unroll
  for (int c = 0; c < CH; ++c) s += wrow[c] * a[c * CH];
  weff[((size_t)b * DIM + p) * DIM + dg] = f2b(s);
}

// ---------------------------------------------------------------------------
extern "C" void kernel_launch(void* const* d_in, const int* in_sizes, int n_in,
                              void* d_out, int out_size, void* d_ws, size_t ws_size,
                              hipStream_t stream) {
  const float* x = (const float*)d_in[0];
  const float* qkv_w = (const float*)d_in[1];
  const float* qkv_b = (const float*)d_in[2];
  const float* dw_w = (const float*)d_in[3];
  const float* dw_b = (const float*)d_in[4];
  const float* proj_w = (const float*)d_in[5];
  const float* proj_b = (const float*)d_in[6];
  const float* temp = (const float*)d_in[7];

  const size_t SZ_C1 = (size_t)BATCH * C3 * HW * 2;       // 301,989,888
  const size_t SZ_WQB = (size_t)C3 * DIM * 2;             // 884,736
  const size_t SZ_SQ = (size_t)BATCH * 2 * DIM * 4;       // 24,576
  const size_t SZ_G = (size_t)BATCH * HEADS * CH * CH * 4;  // 589,824

  const size_t OFF_C1 = 0;
  const size_t OFF_QKVD = OFF_C1 + SZ_C1;
  const size_t OFF_WQB = OFF_QKVD + SZ_C1;
  const size_t OFF_SQ = OFF_WQB + SZ_WQB;
  const size_t OFF_G = OFF_SQ + SZ_SQ;
  const size_t OFF_ATTN = OFF_G + SZ_G;
  const size_t OFF_WEFF = OFF_ATTN + SZ_G;
  const size_t TOTAL = OFF_WEFF + (size_t)BATCH * DIM * DIM * 2;
  if (ws_size < TOTAL) return;  // fail loudly (validation) rather than corrupt

  char* ws = (char*)d_ws;
  ushort* c1 = (ushort*)(ws + OFF_C1);
  ushort* qkvd = (ushort*)(ws + OFF_QKVD);
  ushort* wqb = (ushort*)(ws + OFF_WQB);
  float* sq = (float*)(ws + OFF_SQ);
  float* G = (float*)(ws + OFF_G);
  float* attn = (float*)(ws + OFF_ATTN);
  ushort* weff = (ushort*)(ws + OFF_WEFF);

  hipMemsetAsync(ws + OFF_SQ, 0, SZ_SQ + SZ_G, stream);

  cast_w<<<(C3 * DIM) / 1024, 256, 0, stream>>>(qkv_w, wqb, C3 * DIM);
  // K1: qkv = wqb @ x (+bias), fused x transpose+cast, bf16 out
  gemm_px<float, 1><<<dim3(HW / 64, BATCH), 256, 0, stream>>>(
      wqb, x, qkv_b, (void*)c1, C3, 0L, (long)DIM * HW, (long)C3 * HW);
  dwconv<<<dim3(C3, BATCH), 256, 0, stream>>>(c1, dw_w, dw_b, qkvd, sq);
  gram<<<dim3(16, BATCH * HEADS), 256, 0, stream>>>(qkvd, G);
  softmax_k<<<BATCH * HEADS, 64, 0, stream>>>(G, sq, temp, attn);
  weff_k<<<dim3(DIM, BATCH), 384, 0, stream>>>(proj_w, attn, weff);
  // K4: out = weff @ v (+proj_b), fused v transpose, f32 out
  gemm_px<ushort, 0><<<dim3(HW / 64, BATCH), 256, 0, stream>>>(
      weff, qkvd + (size_t)2 * DIM * HW, proj_b, d_out, DIM,
      (long)DIM * DIM, (long)C3 * HW, (long)DIM * HW);
}